// Round 12
// baseline (1149.213 us; speedup 1.0000x reference)
//
#include <hip/hip_runtime.h>

#define D 128
#define RNUM 7
#define GNUM 64
#define LAYERS 3
#define NBA 4            // dest nodes per aggregation block (16 KB tile)
#define SEG_SHIFT 3      // segments = node*8 + rel (slot 7 empty)
#define KTOT 1024        // combined K: 896 (upd) + 128 (x)

typedef __attribute__((ext_vector_type(8))) short bf16x8;
typedef __attribute__((ext_vector_type(4))) float f32x4;

// ---------- CSR build: histogram over (dest node, rel) segments ----------
__global__ __launch_bounds__(256) void hist_kernel(const int* __restrict__ nout,
    const int* __restrict__ rel, int* __restrict__ hist, int ne) {
  int e = blockIdx.x * 256 + threadIdx.x;
  if (e >= ne) return;
  atomicAdd(&hist[(nout[e] << SEG_SHIFT) | rel[e]], 1);
}

// ---------- scan stage 1 ----------
__global__ __launch_bounds__(256) void scan1_kernel(const int* __restrict__ hist,
    int* __restrict__ row_ptr, int* __restrict__ partials, int nseg) {
  __shared__ int buf[256];
  const int t = threadIdx.x;
  const int base = blockIdx.x * 1024 + t * 4;
  int v0 = 0, v1 = 0, v2 = 0, v3 = 0;
  if (base + 3 < nseg) {
    int4 h4 = *(const int4*)&hist[base];
    v0 = h4.x; v1 = h4.y; v2 = h4.z; v3 = h4.w;
  } else {
    if (base + 0 < nseg) v0 = hist[base + 0];
    if (base + 1 < nseg) v1 = hist[base + 1];
    if (base + 2 < nseg) v2 = hist[base + 2];
    if (base + 3 < nseg) v3 = hist[base + 3];
  }
  int tsum = v0 + v1 + v2 + v3;
  buf[t] = tsum;
  __syncthreads();
  for (int off = 1; off < 256; off <<= 1) {
    int add = (t >= off) ? buf[t - off] : 0;
    __syncthreads();
    buf[t] += add;
    __syncthreads();
  }
  int incl = buf[t];
  int e0 = incl - tsum;
  int e1 = e0 + v0, e2 = e1 + v1, e3 = e2 + v2;
  if (base + 0 < nseg) row_ptr[base + 0] = e0;
  if (base + 1 < nseg) row_ptr[base + 1] = e1;
  if (base + 2 < nseg) row_ptr[base + 2] = e2;
  if (base + 3 < nseg) row_ptr[base + 3] = e3;
  if (t == 255) partials[blockIdx.x] = incl;
}

// ---------- scan stage 2 ----------
__global__ __launch_bounds__(256) void scan2_kernel(int* __restrict__ partials, int nb) {
  __shared__ int buf[256];
  __shared__ int carry_s;
  const int t = threadIdx.x;
  if (t == 0) carry_s = 0;
  __syncthreads();
  for (int c0 = 0; c0 < nb; c0 += 256) {
    int i = c0 + t;
    int v = (i < nb) ? partials[i] : 0;
    buf[t] = v;
    __syncthreads();
    for (int off = 1; off < 256; off <<= 1) {
      int add = (t >= off) ? buf[t - off] : 0;
      __syncthreads();
      buf[t] += add;
      __syncthreads();
    }
    int incl = buf[t];
    int excl = incl - v + carry_s;
    if (i < nb) partials[i] = excl;
    __syncthreads();
    if (t == 255) carry_s += incl;
    __syncthreads();
  }
}

// ---------- scan stage 3 ----------
__global__ __launch_bounds__(256) void scan3_kernel(int* __restrict__ row_ptr,
    int* __restrict__ cursor, const int* __restrict__ partials, int nseg, int ne) {
  int i = blockIdx.x * 256 + threadIdx.x;
  if (i < nseg) {
    int v = row_ptr[i] + partials[i >> 10];
    row_ptr[i] = v;
    cursor[i] = v;
  }
  if (i == 0) row_ptr[nseg] = ne;
}

// ---------- fill: (node_in | rel<<16 | dest_local<<19, ew) ----------
__global__ __launch_bounds__(256) void fill_kernel(const int* __restrict__ nin,
    const int* __restrict__ nout, const int* __restrict__ rel,
    const float* __restrict__ ew, int* __restrict__ cursor,
    int2* __restrict__ erec, int ne) {
  int e = blockIdx.x * 256 + threadIdx.x;
  if (e >= ne) return;
  int r = rel[e];
  int no = nout[e];
  int pos = atomicAdd(&cursor[(no << SEG_SHIFT) | r], 1);
  erec[pos] = make_int2(nin[e] | (r << 16) | ((no & (NBA - 1)) << 19),
                        __float_as_int(ew[e]));
}

__device__ __forceinline__ unsigned int pack_bf2(float a, float b) {
  unsigned int ua = __float_as_uint(a), ub = __float_as_uint(b);
  ua = (ua + 0x7FFFu + ((ua >> 16) & 1u)) >> 16;
  ub = (ub + 0x7FFFu + ((ub >> 16) & 1u)) >> 16;
  return ua | (ub << 16);
}

__device__ __forceinline__ unsigned short bf1(float a) {
  unsigned int u = __float_as_uint(a);
  u = (u + 0x7FFFu + ((u >> 16) & 1u)) >> 16;
  return (unsigned short)u;
}

__device__ __forceinline__ float4 bf4_to_f4(uint2 p) {
  float4 f;
  f.x = __uint_as_float(p.x << 16);
  f.y = __uint_as_float(p.x & 0xFFFF0000u);
  f.z = __uint_as_float(p.y << 16);
  f.w = __uint_as_float(p.y & 0xFFFF0000u);
  return f;
}

__device__ __forceinline__ void fma4(float4& d, float s, const float4& v) {
  d.x += s * v.x; d.y += s * v.y; d.z += s * v.z; d.w += s * v.w;
}

// ---------- W prep: Wt[layer][n][k] = bf16([Wrel;Wloop][k][n]) ----------
__global__ __launch_bounds__(256) void wt_prep_kernel(
    const float* __restrict__ Wrel, const float* __restrict__ Wloop,
    unsigned int* __restrict__ Wt32) {
  int tid = blockIdx.x * 256 + threadIdx.x;
  if (tid >= LAYERS * 128 * 512) return;
  int layer = tid >> 16;
  int rem = tid & 65535;
  int nrow = rem >> 9;
  int k = (rem & 511) * 2;
  float f0, f1;
  if (k < RNUM * D) {
    const float* base = Wrel + (size_t)layer * RNUM * D * D;
    f0 = base[(size_t)k * D + nrow];
    f1 = base[(size_t)(k + 1) * D + nrow];
  } else {
    const float* base = Wloop + (size_t)layer * D * D;
    f0 = base[(size_t)(k - RNUM * D) * D + nrow];
    f1 = base[(size_t)(k + 1 - RNUM * D) * D + nrow];
  }
  Wt32[tid] = pack_bf2(f0, f1);
}

// ---------- init: updx[m][896..1023] = bf16(emb[ut[m]][:]) ----------
__global__ __launch_bounds__(256) void initx_kernel(const int* __restrict__ ut,
    const float* __restrict__ emb, unsigned int* __restrict__ updx32, int n) {
  int tid = blockIdx.x * 256 + threadIdx.x;
  int node = tid >> 4, q = tid & 15;
  if (node >= n) return;
  const float4* E4 = (const float4*)emb;
  int u = ut[node];
  float4 f0 = E4[(size_t)u * 32 + q * 2];
  float4 f1 = E4[(size_t)u * 32 + q * 2 + 1];
  uint4 o;
  o.x = pack_bf2(f0.x, f0.y);
  o.y = pack_bf2(f0.z, f0.w);
  o.z = pack_bf2(f1.x, f1.y);
  o.w = pack_bf2(f1.z, f1.w);
  ((uint4*)&updx32[(size_t)node * 512 + 448])[q] = o;
}

// ---------- edge-parallel aggregation, register segmented-sum ----------
// NBA=4 nodes/block -> 16 KB tile -> occupancy cap 32 waves/CU (was 20).
// 8 streams of 32 lanes sweep disjoint quotas, x8-unrolled gather.
__global__ __launch_bounds__(256) void agg_kernel(
    const int2* __restrict__ erec, const int* __restrict__ row_ptr,
    unsigned int* __restrict__ updx32, int n) {
  __shared__ float acc_s[NBA * 8 * D];   // 16 KB
  const int t = threadIdx.x;
  const int b0 = blockIdx.x * NBA;
#pragma unroll
  for (int i = 0; i < NBA; ++i)
    ((float4*)acc_s)[t + i * 256] = make_float4(0.f, 0.f, 0.f, 0.f);
  __syncthreads();

  int endn = b0 + NBA; if (endn > n) endn = n;
  const int es = row_ptr[b0 << SEG_SHIFT];
  const int ee = row_ptr[endn << SEG_SHIFT];
  const int cnt = ee - es;
  const int s = t >> 5;            // stream 0..7
  const int lane = t & 31;         // 4-elem lane within 128-float row
  const int chunk = (cnt + 7) >> 3;
  int e = es + s * chunk;
  int eend = e + chunk; if (eend > ee) eend = ee;
  const unsigned int* XB = updx32 + 448 + lane * 2;

  if (e < eend) {
    float4 acc = make_float4(0.f, 0.f, 0.f, 0.f);
    bool first = true;
    int2 rec0 = erec[e];
    int curseg = (rec0.x >> 16) & 31;   // rel(3b) | dest_local(2b)

#define FLUSH_SEG() do {                                            \
      float* dst_ = &acc_s[curseg * D + lane * 4];                  \
      if (first) {                                                  \
        atomicAdd(dst_ + 0, acc.x); atomicAdd(dst_ + 1, acc.y);     \
        atomicAdd(dst_ + 2, acc.z); atomicAdd(dst_ + 3, acc.w);     \
        first = false;                                              \
      } else {                                                      \
        *(float4*)dst_ = acc;                                       \
      }                                                             \
      acc = make_float4(0.f, 0.f, 0.f, 0.f);                        \
    } while (0)

#define PROC(rec, p) do {                                           \
      int sg_ = ((rec).x >> 16) & 31;                               \
      if (sg_ != curseg) { FLUSH_SEG(); curseg = sg_; }             \
      fma4(acc, __int_as_float((rec).y), bf4_to_f4(p));             \
    } while (0)

    for (; e + 7 < eend; e += 8) {
      int2 r0 = erec[e];
      int2 r1 = erec[e + 1];
      int2 r2 = erec[e + 2];
      int2 r3 = erec[e + 3];
      int2 r4 = erec[e + 4];
      int2 r5 = erec[e + 5];
      int2 r6 = erec[e + 6];
      int2 r7 = erec[e + 7];
      uint2 p0 = *(const uint2*)(XB + (size_t)(r0.x & 0xFFFF) * 512);
      uint2 p1 = *(const uint2*)(XB + (size_t)(r1.x & 0xFFFF) * 512);
      uint2 p2 = *(const uint2*)(XB + (size_t)(r2.x & 0xFFFF) * 512);
      uint2 p3 = *(const uint2*)(XB + (size_t)(r3.x & 0xFFFF) * 512);
      uint2 p4 = *(const uint2*)(XB + (size_t)(r4.x & 0xFFFF) * 512);
      uint2 p5 = *(const uint2*)(XB + (size_t)(r5.x & 0xFFFF) * 512);
      uint2 p6 = *(const uint2*)(XB + (size_t)(r6.x & 0xFFFF) * 512);
      uint2 p7 = *(const uint2*)(XB + (size_t)(r7.x & 0xFFFF) * 512);
      PROC(r0, p0); PROC(r1, p1); PROC(r2, p2); PROC(r3, p3);
      PROC(r4, p4); PROC(r5, p5); PROC(r6, p6); PROC(r7, p7);
    }
    for (; e < eend; ++e) {
      int2 r0 = erec[e];
      uint2 p0 = *(const uint2*)(XB + (size_t)(r0.x & 0xFFFF) * 512);
      PROC(r0, p0);
    }
    {
      float* dst_ = &acc_s[curseg * D + lane * 4];
      atomicAdd(dst_ + 0, acc.x); atomicAdd(dst_ + 1, acc.y);
      atomicAdd(dst_ + 2, acc.z); atomicAdd(dst_ + 3, acc.w);
    }
#undef PROC
#undef FLUSH_SEG
  }
  __syncthreads();

  // flush tile -> updx rows (stride 512 uints), cols 0..447 (bf16 pairs)
  // NBA*448 = 1792 uints, 7 per thread
  const int nvalid = endn - b0;
#pragma unroll
  for (int i = 0; i < 7; ++i) {
    int idx = t + i * 256;
    int node = idx / 448;
    int w448 = idx - node * 448;
    int rel = w448 >> 6;
    int k = (w448 * 2) & 127;
    if (node < nvalid) {
      float f0 = acc_s[((node << 3) | rel) * D + k];
      float f1 = acc_s[((node << 3) | rel) * D + k + 1];
      updx32[(size_t)(b0 + node) * 512 + w448] = pack_bf2(f0, f1);
    }
  }
}

// ---------- MFMA transform, register double-buffered ----------
// Block = 32 rows (4 waves); wave = 16 rows x 64 cols (1 A-frag, 4 B-frags,
// 4 MFMAs per K-chunk). Grid 2x vs round 11 -> 6 blocks/CU for latency hiding.
__global__ __launch_bounds__(256) void xform_kernel(
    unsigned short* __restrict__ updx, const unsigned short* __restrict__ Wt,
    const float* __restrict__ brel, const float* __restrict__ bloop,
    float* __restrict__ hout, int n, int write_fp32) {
  const int t = threadIdx.x;
  const int w = t >> 6, lane = t & 63;
  const int rg = w >> 1, cg = w & 1;
  const int m0 = blockIdx.x * 32 + rg * 16;
  const int rt = lane & 15, quad = lane >> 4;

  const unsigned short* a0 = updx + (size_t)(m0 + rt) * KTOT + quad * 8;
  const unsigned short* b0 = Wt + (size_t)(cg * 64 + rt) * KTOT + quad * 8;
  const unsigned short* b1 = b0 + (size_t)16 * KTOT;
  const unsigned short* b2 = b0 + (size_t)32 * KTOT;
  const unsigned short* b3 = b0 + (size_t)48 * KTOT;

  f32x4 acc[4];
#pragma unroll
  for (int c = 0; c < 4; ++c) acc[c] = (f32x4){0.f, 0.f, 0.f, 0.f};

  bf16x8 A0 = *(const bf16x8*)a0;
  bf16x8 B0 = *(const bf16x8*)b0;
  bf16x8 B1 = *(const bf16x8*)b1;
  bf16x8 B2 = *(const bf16x8*)b2;
  bf16x8 B3 = *(const bf16x8*)b3;

  for (int kc = 32; kc <= KTOT; kc += 32) {
    // prefetch next chunk (last iter reads 16B past the row: mapped ws)
    bf16x8 nA0 = *(const bf16x8*)(a0 + kc);
    bf16x8 nB0 = *(const bf16x8*)(b0 + kc);
    bf16x8 nB1 = *(const bf16x8*)(b1 + kc);
    bf16x8 nB2 = *(const bf16x8*)(b2 + kc);
    bf16x8 nB3 = *(const bf16x8*)(b3 + kc);

    acc[0] = __builtin_amdgcn_mfma_f32_16x16x32_bf16(A0, B0, acc[0], 0, 0, 0);
    acc[1] = __builtin_amdgcn_mfma_f32_16x16x32_bf16(A0, B1, acc[1], 0, 0, 0);
    acc[2] = __builtin_amdgcn_mfma_f32_16x16x32_bf16(A0, B2, acc[2], 0, 0, 0);
    acc[3] = __builtin_amdgcn_mfma_f32_16x16x32_bf16(A0, B3, acc[3], 0, 0, 0);

    A0 = nA0; B0 = nB0; B1 = nB1; B2 = nB2; B3 = nB3;
  }

  __syncthreads();   // all K-reads in block done before x-section overwrite

  // C/D layout: col = lane&15, row = quad*4 + reg
#pragma unroll
  for (int cc = 0; cc < 4; ++cc) {
    int col = cg * 64 + cc * 16 + rt;
    float bias = brel[col] + bloop[col];
#pragma unroll
    for (int r = 0; r < 4; ++r) {
      int m = m0 + quad * 4 + r;
      if (m < n) {
        float v = fmaxf(acc[cc][r] + bias, 0.f);
        if (write_fp32) hout[(size_t)m * D + col] = v;
        else updx[(size_t)m * KTOT + 896 + col] = bf1(v);
      }
    }
  }
}

// ---------- graph pooling (node2graph sorted) ----------
__global__ __launch_bounds__(256) void pool_kernel(const float* __restrict__ x,
    const int* __restrict__ n2g, float* __restrict__ gf, int n) {
  int d = threadIdx.x & 127;
  int sub = threadIdx.x >> 7;
  int n0 = (blockIdx.x * 2 + sub) * 128;
  int nend = n0 + 128;
  if (nend > n) nend = n;
  float acc = 0.f;
  int gcur = -1;
  for (int i = n0; i < nend; ++i) {
    int g = n2g[i];
    if (g != gcur) {
      if (gcur >= 0) atomicAdd(&gf[gcur * D + d], acc);
      gcur = g;
      acc = 0.f;
    }
    acc += x[(size_t)i * D + d];
  }
  if (gcur >= 0) atomicAdd(&gf[gcur * D + d], acc);
}

extern "C" void kernel_launch(void* const* d_in, const int* in_sizes, int n_in,
                              void* d_out, int out_size, void* d_ws, size_t ws_size,
                              hipStream_t stream) {
  const int*   unit_type  = (const int*)d_in[0];
  const int*   node_in    = (const int*)d_in[1];
  const int*   node_out   = (const int*)d_in[2];
  const int*   relation   = (const int*)d_in[3];
  const float* edge_w     = (const float*)d_in[4];
  const int*   node2graph = (const int*)d_in[5];
  const float* emb        = (const float*)d_in[6];
  const float* W_rel      = (const float*)d_in[7];
  const float* b_rel      = (const float*)d_in[8];
  const float* W_loop     = (const float*)d_in[9];
  const float* b_loop     = (const float*)d_in[10];

  const int n  = in_sizes[0];
  const int ne = in_sizes[1];
  float* out = (float*)d_out;

  const int nseg = n << SEG_SHIFT;
  const int nb   = (nseg + 1023) / 1024;

  // workspace layout
  unsigned short* updx     = (unsigned short*)d_ws;               // N x 1024 bf16
  unsigned short* Wt       = updx + (size_t)n * KTOT;             // 3 x 128 x 1024 bf16
  int2*           erec     = (int2*)(Wt + (size_t)LAYERS * D * KTOT);
  int*            hist     = (int*)(erec + ne);
  int*            row_ptr  = hist + nseg;
  int*            cursor   = row_ptr + ((nseg + 4) & ~3);
  int*            partials = cursor + nseg;

  hipMemsetAsync(d_out, 0, (size_t)GNUM * D * sizeof(float), stream);
  hipMemsetAsync(hist, 0, (size_t)nseg * sizeof(int), stream);

  const int eblocks = (ne + 255) / 256;
  hist_kernel<<<eblocks, 256, 0, stream>>>(node_out, relation, hist, ne);
  scan1_kernel<<<nb, 256, 0, stream>>>(hist, row_ptr, partials, nseg);
  scan2_kernel<<<1, 256, 0, stream>>>(partials, nb);
  scan3_kernel<<<(nseg + 255) / 256, 256, 0, stream>>>(row_ptr, cursor, partials, nseg, ne);
  fill_kernel<<<eblocks, 256, 0, stream>>>(node_in, node_out, relation, edge_w,
                                           cursor, erec, ne);

  wt_prep_kernel<<<(LAYERS * 128 * 512 + 255) / 256, 256, 0, stream>>>(
      W_rel, W_loop, (unsigned int*)Wt);

  initx_kernel<<<(n * 16 + 255) / 256, 256, 0, stream>>>(
      unit_type, emb, (unsigned int*)updx, n);

  const int ablocks = (n + NBA - 1) / NBA;
  const int tblocks = (n + 31) / 32;
  float* xfinal = out + GNUM * D;
  for (int i = 0; i < LAYERS; ++i) {
    agg_kernel<<<ablocks, 256, 0, stream>>>(erec, row_ptr,
                                            (unsigned int*)updx, n);
    xform_kernel<<<tblocks, 256, 0, stream>>>(
        updx, Wt + (size_t)i * D * KTOT,
        b_rel + (size_t)i * D, b_loop + (size_t)i * D,
        xfinal, n, (i == LAYERS - 1) ? 1 : 0);
  }

  pool_kernel<<<(n + 255) / 256, 256, 0, stream>>>(xfinal, node2graph, out, n);
}